// Round 10
// baseline (269.457 us; speedup 1.0000x reference)
//
#include <hip/hip_runtime.h>
#include <math.h>

#define DIM 160
#define NB 2
#define CHUNK 10
#define NCHZ (DIM / CHUNK)   // 16
#define NTHREADS 256
#define EPS_F 1.1920928955078125e-07f

typedef float v4f __attribute__((ext_vector_type(4)));

#define SBAR() __builtin_amdgcn_sched_barrier(0)
// Hard register-use: forces the loaded value to exist here (waitcnt lands here),
// and creates a data dep no scheduler/regalloc pass can sink the load past.
#define USE4(x) asm volatile("" :: "v"(x))
#define USEBUF(B) do { USE4(B[0]); USE4(B[1]); USE4(B[2]); USE4(B[3]); \
                       USE4(B[4]); USE4(B[5]); USE4(B[6]); USE4(B[7]); USE4(B[8]); } while (0)

__device__ __forceinline__ int imin(int a, int b) { return a < b ? a : b; }
__device__ __forceinline__ int imax(int a, int b) { return a > b ? a : b; }

// ws layout (doubles):
// [0..1] sum_mask[n], [2..3] sum_norm_pred[n], [4..5] sum_norm_tgt[n],
// [6] sum inner^2, [8..9] c_pred[n], [10..11] c_tgt[n]

// Issue one plane's 9 aligned float4 loads (rows y-1,y,y+1 x {L,M,R}).
// Addresses clamped (always legal); edge taps zeroed at compute time (R8-validated).
__device__ __forceinline__ void issue_plane(const float* __restrict__ img, int zoff,
                                            int ro0, int ro1, int ro2,
                                            int xL, int xM, int xR, v4f (&B)[9]) {
  const float* r0 = img + zoff + ro0;
  const float* r1 = img + zoff + ro1;
  const float* r2 = img + zoff + ro2;
  B[0] = *(const v4f*)(r0 + xL); B[1] = *(const v4f*)(r0 + xM); B[2] = *(const v4f*)(r0 + xR);
  B[3] = *(const v4f*)(r1 + xL); B[4] = *(const v4f*)(r1 + xM); B[5] = *(const v4f*)(r1 + xR);
  B[6] = *(const v4f*)(r2 + xL); B[7] = *(const v4f*)(r2 + xM); B[8] = *(const v4f*)(r2 + xR);
}

// P1 = diff_x*smooth_y, P2 = smooth_x*diff_y, P3 = smooth_x*smooth_y for 4 voxels.
__device__ __forceinline__ void compute_P(const v4f (&B)[9],
                                          float rf0, float rf1, float rf2,
                                          float fxl, float fxr,
                                          float (&P1)[4], float (&P2)[4], float (&P3)[4]) {
#pragma unroll
  for (int r = 0; r < 3; ++r) {
    const float rf = (r == 0) ? rf0 : (r == 1) ? rf1 : rf2;
    const v4f L = B[r * 3 + 0], M = B[r * 3 + 1], R = B[r * 3 + 2];
    const float fm1 = L.w * fxl, f0 = M.x, f1 = M.y, f2 = M.z, f3 = M.w, f4 = R.x * fxr;
    float S[4], D[4];
    S[0] = (fm1 + 2.f * f0 + f1) * rf;  D[0] = (f1 - fm1) * rf;
    S[1] = (f0 + 2.f * f1 + f2) * rf;   D[1] = (f2 - f0) * rf;
    S[2] = (f1 + 2.f * f2 + f3) * rf;   D[2] = (f3 - f1) * rf;
    S[3] = (f2 + 2.f * f3 + f4) * rf;   D[3] = (f4 - f2) * rf;
    if (r == 0) {
#pragma unroll
      for (int j = 0; j < 4; ++j) { P1[j] = D[j]; P2[j] = -S[j]; P3[j] = S[j]; }
    } else if (r == 1) {
#pragma unroll
      for (int j = 0; j < 4; ++j) { P1[j] += 2.f * D[j]; P3[j] += 2.f * S[j]; }
    } else {
#pragma unroll
      for (int j = 0; j < 4; ++j) { P1[j] += D[j]; P2[j] += S[j]; P3[j] += S[j]; }
    }
  }
}

// One pass1 step: [USE(cur); issue(nxt); mask] | SBAR | [compute(cur)] | SBAR.
#define P1STEP(K, CUR, NXT, MC, MN)                                              \
  do {                                                                           \
    USEBUF(CUR);                                                                 \
    if ((K) <= CHUNK)                                                            \
      issue_plane(img, imin(zs + (K), DIM - 1) * DIM * DIM,                      \
                  ro0, ro1, ro2, xL, xM, xR, NXT);                               \
    if (im == 0 && (K) >= 1 && (K) <= CHUNK)                                     \
      MN = *(const v4f*)(mb + ((zs + (K) - 1) * DIM + y) * DIM + xb);            \
    SBAR();                                                                      \
    {                                                                            \
      const float fz = ((unsigned)(zs - 1 + (K)) < DIM) ? 1.f : 0.f;             \
      float P1a[4], P2a[4], P3a[4];                                              \
      compute_P(CUR, fz * fym, fz, fz * fyp, fxl, fxr, P1a, P2a, P3a);           \
      const int sA = (K) & 1, sB = sA ^ 1;                                       \
      if ((K) >= 2) {                                                            \
        if (im == 0) {                                                           \
          const v4f mv = MC;                                                     \
          _Pragma("unroll")                                                      \
          for (int j = 0; j < 4; ++j) {                                          \
            const float mj = (j == 0) ? mv.x : (j == 1) ? mv.y : (j == 2) ? mv.z : mv.w; \
            float gx = OUT[sA][0][j] + P1a[j];                                   \
            float gy = OUT[sA][1][j] + P2a[j];                                   \
            float gz = OUT[sA][2][j] + P3a[j];                                   \
            am += mj;                                                            \
            an += sqrtf(gx * gx + gy * gy + gz * gz + EPS_F) * mj;               \
          }                                                                      \
        } else {                                                                 \
          _Pragma("unroll")                                                      \
          for (int j = 0; j < 4; ++j) {                                          \
            float gx = OUT[sA][0][j] + P1a[j];                                   \
            float gy = OUT[sA][1][j] + P2a[j];                                   \
            float gz = OUT[sA][2][j] + P3a[j];                                   \
            an += sqrtf(gx * gx + gy * gy + gz * gz + EPS_F);                    \
          }                                                                      \
        }                                                                        \
      }                                                                          \
      _Pragma("unroll")                                                          \
      for (int j = 0; j < 4; ++j) {                                              \
        OUT[sA][0][j] = P1a[j];                                                  \
        OUT[sA][1][j] = P2a[j];                                                  \
        OUT[sA][2][j] = -P3a[j];                                                 \
        OUT[sB][0][j] += 2.f * P1a[j];                                           \
        OUT[sB][1][j] += 2.f * P2a[j];                                           \
      }                                                                          \
    }                                                                            \
    SBAR();                                                                      \
  } while (0)

__global__ __launch_bounds__(NTHREADS)
void pass1_kernel(const float* __restrict__ pred, const float* __restrict__ tgt,
                  const float* __restrict__ mask, double* __restrict__ ws) {
  __shared__ float red[2][4];
  const int tid = threadIdx.x;
  const int tx = tid & 7, ty = tid >> 3;
  int bz = blockIdx.z;
  const int im = bz & 1; bz >>= 1;
  const int n = bz / NCHZ;
  const int zs = (bz % NCHZ) * CHUNK;
  const int xb = blockIdx.x * 32 + tx * 4;
  const int y = blockIdx.y * 32 + ty;
  const size_t base = (size_t)n * DIM * DIM * DIM;
  const float* img = (im == 0 ? pred : tgt) + base;
  const float* mb = mask + base;

  const float fxl = (xb >= 4) ? 1.f : 0.f;
  const float fxr = (xb + 4 < DIM) ? 1.f : 0.f;
  const float fym = (y >= 1) ? 1.f : 0.f;
  const float fyp = (y <= DIM - 2) ? 1.f : 0.f;

  const int ro0 = imax(y - 1, 0) * DIM;
  const int ro1 = y * DIM;
  const int ro2 = imin(y + 1, DIM - 1) * DIM;
  const int xL = imax(xb - 4, 0), xM = xb, xR = imin(xb + 4, DIM - 4);

  float OUT[2][3][4];
#pragma unroll
  for (int s = 0; s < 2; ++s)
#pragma unroll
    for (int f = 0; f < 3; ++f)
#pragma unroll
      for (int j = 0; j < 4; ++j) OUT[s][f][j] = 0.f;

  float am = 0.f, an = 0.f;
  v4f BUFA[9], BUFB[9];
  v4f MVA = (v4f)(0.f), MVB = (v4f)(0.f);

  issue_plane(img, imin(imax(zs - 1, 0), DIM - 1) * DIM * DIM,
              ro0, ro1, ro2, xL, xM, xR, BUFA);

  P1STEP(0,  BUFA, BUFB, MVA, MVB);
  P1STEP(1,  BUFB, BUFA, MVB, MVA);
  P1STEP(2,  BUFA, BUFB, MVA, MVB);
  P1STEP(3,  BUFB, BUFA, MVB, MVA);
  P1STEP(4,  BUFA, BUFB, MVA, MVB);
  P1STEP(5,  BUFB, BUFA, MVB, MVA);
  P1STEP(6,  BUFA, BUFB, MVA, MVB);
  P1STEP(7,  BUFB, BUFA, MVB, MVA);
  P1STEP(8,  BUFA, BUFB, MVA, MVB);
  P1STEP(9,  BUFB, BUFA, MVB, MVA);
  P1STEP(10, BUFA, BUFB, MVA, MVB);
  P1STEP(11, BUFB, BUFA, MVB, MVA);

  float v0 = am, v1 = an;
#pragma unroll
  for (int off = 32; off > 0; off >>= 1) {
    v0 += __shfl_down(v0, off, 64);
    v1 += __shfl_down(v1, off, 64);
  }
  const int lane = tid & 63, wave = tid >> 6;
  if (lane == 0) { red[0][wave] = v0; red[1][wave] = v1; }
  __syncthreads();
  if (tid == 0) {
    if (im == 0) atomicAdd(&ws[0 + n], (double)(red[0][0] + red[0][1] + red[0][2] + red[0][3]));
    atomicAdd(&ws[2 + 2 * im + n], (double)(red[1][0] + red[1][1] + red[1][2] + red[1][3]));
  }
}

__global__ void compute_c_kernel(double* __restrict__ ws) {
  if (threadIdx.x == 0 && blockIdx.x == 0) {
    for (int n = 0; n < NB; ++n) {
      double inv_m = 1.0 / ws[0 + n];
      double ae_p = ws[2 + n] * inv_m;  // eta = 1.0
      double ae_t = ws[4 + n] * inv_m;
      ws[8 + n] = ae_p * ae_p + (double)EPS_F;
      ws[10 + n] = ae_t * ae_t + (double)EPS_F;
    }
  }
}

// Pass2 step: wait pred cur (tgt cur in flight) -> compute pred, reissue pred;
// wait tgt cur (pred next in flight) -> compute tgt, reissue tgt; combine.
#define P2STEP(K)                                                                \
  do {                                                                           \
    const float fz = ((unsigned)(zs - 1 + (K)) < DIM) ? 1.f : 0.f;               \
    const int znoff = imin(zs + (K), DIM - 1) * DIM * DIM;                       \
    USEBUF(PBUF);                                                                \
    SBAR();                                                                      \
    float Pp1[4], Pp2[4], Pp3[4];                                                \
    compute_P(PBUF, fz * fym, fz, fz * fyp, fxl, fxr, Pp1, Pp2, Pp3);            \
    SBAR();                                                                      \
    if ((K) <= CHUNK) issue_plane(pb, znoff, ro0, ro1, ro2, xL, xM, xR, PBUF);   \
    USEBUF(TBUF);                                                                \
    SBAR();                                                                      \
    float Pt1[4], Pt2[4], Pt3[4];                                                \
    compute_P(TBUF, fz * fym, fz, fz * fyp, fxl, fxr, Pt1, Pt2, Pt3);            \
    SBAR();                                                                      \
    if ((K) <= CHUNK) issue_plane(tb, znoff, ro0, ro1, ro2, xL, xM, xR, TBUF);   \
    SBAR();                                                                      \
    const int sA = (K) & 1, sB = sA ^ 1;                                         \
    if ((K) >= 2) {                                                              \
      _Pragma("unroll")                                                          \
      for (int j = 0; j < 4; ++j) {                                              \
        float gpx = OUT[sA][0][0][j] + Pp1[j];                                   \
        float gpy = OUT[sA][0][1][j] + Pp2[j];                                   \
        float gpz = OUT[sA][0][2][j] + Pp3[j];                                   \
        float gtx = OUT[sA][1][0][j] + Pt1[j];                                   \
        float gty = OUT[sA][1][1][j] + Pt2[j];                                   \
        float gtz = OUT[sA][1][2][j] + Pt3[j];                                   \
        float sqp = gpx * gpx + gpy * gpy + gpz * gpz;                           \
        float sqt = gtx * gtx + gty * gty + gtz * gtz;                           \
        float dot = gpx * gtx + gpy * gty + gpz * gtz;                           \
        float inner = dot * rsqrtf((sqp + cp) * (sqt + ct));                     \
        acc += inner * inner;                                                    \
      }                                                                          \
    }                                                                            \
    _Pragma("unroll")                                                            \
    for (int j = 0; j < 4; ++j) {                                                \
      OUT[sA][0][0][j] = Pp1[j];                                                 \
      OUT[sA][0][1][j] = Pp2[j];                                                 \
      OUT[sA][0][2][j] = -Pp3[j];                                                \
      OUT[sB][0][0][j] += 2.f * Pp1[j];                                          \
      OUT[sB][0][1][j] += 2.f * Pp2[j];                                          \
      OUT[sA][1][0][j] = Pt1[j];                                                 \
      OUT[sA][1][1][j] = Pt2[j];                                                 \
      OUT[sA][1][2][j] = -Pt3[j];                                                \
      OUT[sB][1][0][j] += 2.f * Pt1[j];                                          \
      OUT[sB][1][1][j] += 2.f * Pt2[j];                                          \
    }                                                                            \
  } while (0)

__global__ __launch_bounds__(NTHREADS)
void pass2_kernel(const float* __restrict__ pred, const float* __restrict__ tgt,
                  double* __restrict__ ws) {
  __shared__ float red[4];
  const int tid = threadIdx.x;
  const int tx = tid & 7, ty = tid >> 3;
  const int bz = blockIdx.z;
  const int n = bz / NCHZ;
  const int zs = (bz % NCHZ) * CHUNK;
  const int xb = blockIdx.x * 32 + tx * 4;
  const int y = blockIdx.y * 32 + ty;
  const size_t base = (size_t)n * DIM * DIM * DIM;
  const float* pb = pred + base;
  const float* tb = tgt + base;

  const float cp = (float)ws[8 + n];
  const float ct = (float)ws[10 + n];

  const float fxl = (xb >= 4) ? 1.f : 0.f;
  const float fxr = (xb + 4 < DIM) ? 1.f : 0.f;
  const float fym = (y >= 1) ? 1.f : 0.f;
  const float fyp = (y <= DIM - 2) ? 1.f : 0.f;

  const int ro0 = imax(y - 1, 0) * DIM;
  const int ro1 = y * DIM;
  const int ro2 = imin(y + 1, DIM - 1) * DIM;
  const int xL = imax(xb - 4, 0), xM = xb, xR = imin(xb + 4, DIM - 4);

  float OUT[2][2][3][4];  // [slot][img][field][j]
#pragma unroll
  for (int s = 0; s < 2; ++s)
#pragma unroll
    for (int g = 0; g < 2; ++g)
#pragma unroll
      for (int f = 0; f < 3; ++f)
#pragma unroll
        for (int j = 0; j < 4; ++j) OUT[s][g][f][j] = 0.f;

  float acc = 0.f;
  v4f PBUF[9], TBUF[9];

  {
    const int z0off = imin(imax(zs - 1, 0), DIM - 1) * DIM * DIM;
    issue_plane(pb, z0off, ro0, ro1, ro2, xL, xM, xR, PBUF);
    issue_plane(tb, z0off, ro0, ro1, ro2, xL, xM, xR, TBUF);
  }

  P2STEP(0);
  P2STEP(1);
  P2STEP(2);
  P2STEP(3);
  P2STEP(4);
  P2STEP(5);
  P2STEP(6);
  P2STEP(7);
  P2STEP(8);
  P2STEP(9);
  P2STEP(10);
  P2STEP(11);

#pragma unroll
  for (int off = 32; off > 0; off >>= 1) acc += __shfl_down(acc, off, 64);
  const int lane = tid & 63, wave = tid >> 6;
  if (lane == 0) red[wave] = acc;
  __syncthreads();
  if (tid == 0) atomicAdd(&ws[6], (double)(red[0] + red[1] + red[2] + red[3]));
}

__global__ void finalize_kernel(const double* __restrict__ ws, float* __restrict__ out) {
  if (threadIdx.x == 0 && blockIdx.x == 0) {
    double mean = ws[6] / ((double)NB * DIM * DIM * DIM);
    out[0] = (float)(1.0 - mean);
  }
}

extern "C" void kernel_launch(void* const* d_in, const int* in_sizes, int n_in,
                              void* d_out, int out_size, void* d_ws, size_t ws_size,
                              hipStream_t stream) {
  const float* pred = (const float*)d_in[0];
  const float* tgt = (const float*)d_in[1];
  const float* mask = (const float*)d_in[2];
  float* out = (float*)d_out;
  double* ws = (double*)d_ws;

  hipMemsetAsync(d_ws, 0, 16 * sizeof(double), stream);

  dim3 grid1(DIM / 32, DIM / 32, NCHZ * NB * 2);  // 5 x 5 x 64 = 1600 blocks
  pass1_kernel<<<grid1, NTHREADS, 0, stream>>>(pred, tgt, mask, ws);
  compute_c_kernel<<<1, 64, 0, stream>>>(ws);
  dim3 grid2(DIM / 32, DIM / 32, NCHZ * NB);      // 5 x 5 x 32 = 800 blocks
  pass2_kernel<<<grid2, NTHREADS, 0, stream>>>(pred, tgt, ws);
  finalize_kernel<<<1, 64, 0, stream>>>(ws, out);
}